// Round 18
// baseline (126.019 us; speedup 1.0000x reference)
//
#include <hip/hip_runtime.h>

#define NB 256
#define NO 10
#define NI 1152
#define NK 8
#define ND 16
#define PCH 144   // i-chunks for pass0/dotacc (PIC=8)
#define PIC 8

typedef unsigned short u16;
typedef unsigned int u32;
typedef __attribute__((ext_vector_type(8))) short s8v;   // 8 bf16 (MFMA A/B frag)
typedef __attribute__((ext_vector_type(4))) float f4v;   // MFMA C/D frag

__device__ __forceinline__ float bf2f(u16 h){ return __uint_as_float(((u32)h) << 16); }
__device__ __forceinline__ u16 f2bf(float f){
  u32 u = __float_as_uint(f);
  return (u16)((u + 0x7FFFu + ((u >> 16) & 1u)) >> 16);  // RNE
}
__device__ __forceinline__ u32 cvt_pk_bf16(float lo, float hi){
  u32 r;
  asm("v_cvt_pk_bf16_f32 %0, %1, %2" : "=v"(r) : "v"(lo), "v"(hi));
  return r;
}
__device__ __forceinline__ s8v zero8(){
  s8v z;
  #pragma unroll
  for (int j = 0; j < 8; ++j) z[j] = 0;
  return z;
}

// prep: blocks [0,288): x [b][i][k] f32 -> xbf [i][b][k] bf16 via LDS 32x32 tile
//       blocks [288,1008): W [o][i][d][k] -> Wb (same layout) + WTb [o][i][k][d]
__global__ __launch_bounds__(256) void k_prep(const float* __restrict__ x,
                                              const float* __restrict__ W,
                                              u16* __restrict__ xbf,
                                              u16* __restrict__ Wb,
                                              u16* __restrict__ WTb){
  int blk = blockIdx.x;
  if (blk < 288){
    __shared__ __align__(16) u16 tile[32][33][8];
    int i0 = (blk >> 3) * 32, b0 = (blk & 7) * 32;
    int t = threadIdx.x;
    int bl = t >> 3, seg = t & 7;    // phase 1: thread = (b-local, 4-i segment)
    const float* src = x + ((size_t)(b0 + bl) * NI + (i0 + seg * 4)) * NK;
    #pragma unroll
    for (int q = 0; q < 4; ++q){
      float4 v0 = *(const float4*)(src + q * 8);
      float4 v1 = *(const float4*)(src + q * 8 + 4);
      *(uint4*)(&tile[seg * 4 + q][bl][0]) =
        make_uint4(cvt_pk_bf16(v0.x, v0.y), cvt_pk_bf16(v0.z, v0.w),
                   cvt_pk_bf16(v1.x, v1.y), cvt_pk_bf16(v1.z, v1.w));
    }
    __syncthreads();
    int il = t >> 3, sb2 = t & 7;    // phase 2: thread = (i-local, 4-b segment)
    u16* dst = xbf + ((size_t)(i0 + il) * NB + b0 + sb2 * 4) * NK;
    #pragma unroll
    for (int q = 0; q < 4; ++q)
      *(uint4*)(dst + q * 8) = *(const uint4*)(&tile[il][sb2 * 4 + q][0]);
  } else {
    int t = (blk - 288) * 256 + threadIdx.x;   // one (o,i,d) row of 8 k per thread
    if (t < NO * NI * ND){
      int oi = t >> 4, d = t & 15;
      const float* src = W + (size_t)t * NK;
      float4 v0 = *(const float4*)(src);
      float4 v1 = *(const float4*)(src + 4);
      u32 p0 = cvt_pk_bf16(v0.x, v0.y), p1 = cvt_pk_bf16(v0.z, v0.w);
      u32 p2 = cvt_pk_bf16(v1.x, v1.y), p3 = cvt_pk_bf16(v1.z, v1.w);
      *(uint4*)(Wb + (size_t)t * NK) = make_uint4(p0, p1, p2, p3);
      u16 e[8] = {(u16)(p0 & 0xffff), (u16)(p0 >> 16), (u16)(p1 & 0xffff), (u16)(p1 >> 16),
                  (u16)(p2 & 0xffff), (u16)(p2 >> 16), (u16)(p3 & 0xffff), (u16)(p3 >> 16)};
      #pragma unroll
      for (int k = 0; k < 8; ++k)
        WTb[((size_t)oi * NK + k) * ND + d] = e[k];
    }
  }
}

// pass0: u-tiles via MFMA; usq bf16 [o][i][b]; Pq[(o*4+g)*PCH+ch][b] = 4xbf16(0.1*sum_i u)
// 1D grid 1440, XCD-swizzled (bijective)
__global__ __launch_bounds__(256) void k_pass0(const u16* __restrict__ xbf,
                                               const u16* __restrict__ Wb,
                                               u16* __restrict__ usq,
                                               uint2* __restrict__ Pq){
  int bid = blockIdx.x;
  int swz = (bid & 7) * 180 + (bid >> 3);   // bijective: 1440 = 8*180
  int o = swz % NO, ch = swz / NO, i0 = ch * PIC;
  int w = threadIdx.x >> 6, l = threadIdx.x & 63, g = l >> 4, col = l & 15;
  float s0[4][4];
  #pragma unroll
  for (int bt = 0; bt < 4; ++bt){
    #pragma unroll
    for (int j = 0; j < 4; ++j) s0[bt][j] = 0.f;
  }
  #pragma unroll
  for (int ii = 0; ii < PIC; ++ii){
    int i = i0 + ii;
    s8v a = zero8();
    if (g == 0)  // A[d=col][k=j]
      a = *(const s8v*)(Wb + ((size_t)(o * NI + i) * ND + col) * NK);
    #pragma unroll
    for (int bt = 0; bt < 4; ++bt){
      int b = (w * 4 + bt) * 16 + col;
      s8v bf = zero8();
      if (g == 0)  // B[k=j][n=col] = x[i][b][j]
        bf = *(const s8v*)(xbf + ((size_t)i * NB + b) * NK);
      f4v c = {0.f, 0.f, 0.f, 0.f};
      c = __builtin_amdgcn_mfma_f32_16x16x32_bf16(a, bf, c, 0, 0, 0);
      float uq = c[0]*c[0] + c[1]*c[1] + c[2]*c[2] + c[3]*c[3];
      uq += __shfl_xor(uq, 16);
      uq += __shfl_xor(uq, 32);
      if (g == 0) usq[((size_t)o * NI + i) * NB + b] = f2bf(uq);
      #pragma unroll
      for (int j = 0; j < 4; ++j) s0[bt][j] += c[j];
    }
  }
  #pragma unroll
  for (int bt = 0; bt < 4; ++bt){
    int b = (w * 4 + bt) * 16 + col;
    uint2 v = make_uint2(cvt_pk_bf16(0.1f * s0[bt][0], 0.1f * s0[bt][1]),
                         cvt_pk_bf16(0.1f * s0[bt][2], 0.1f * s0[bt][3]));
    Pq[((size_t)(o * 4 + g) * PCH + ch) * NB + b] = v;
  }
}

// red: grid (NO, 8); 512 thr = bl(32) x dq(4) x chq(4); 36 ch each + LDS 4-way combine.
// !LAST -> Sbt bf16 [o][b][d]; LAST -> squash -> out (k_final fused)
template<bool LAST>
__global__ __launch_bounds__(512) void k_red(const uint2* __restrict__ Pq,
                                             u16* __restrict__ Sbt,
                                             float* __restrict__ out){
  int o = blockIdx.x, bs = blockIdx.y;
  int bl = threadIdx.x & 31, dq = (threadIdx.x >> 5) & 3, chq = threadIdx.x >> 7;
  int b = bs * 32 + bl;
  const uint2* p = Pq + ((size_t)(o * 4 + dq) * PCH + chq * (PCH / 4)) * NB + b;
  float4 a = make_float4(0.f, 0.f, 0.f, 0.f);
  #pragma unroll 12
  for (int ch = 0; ch < PCH / 4; ++ch){
    uint2 v = p[(size_t)ch * NB];
    a.x += bf2f((u16)(v.x & 0xffff));
    a.y += bf2f((u16)(v.x >> 16));
    a.z += bf2f((u16)(v.y & 0xffff));
    a.w += bf2f((u16)(v.y >> 16));
  }
  __shared__ float4 tmp[3][4][32];   // partials from chq=1..3: [chq-1][dq][bl]
  if (chq) tmp[chq - 1][dq][bl] = a;
  __syncthreads();
  if (chq == 0){
    #pragma unroll
    for (int q = 0; q < 3; ++q){
      float4 v = tmp[q][dq][bl];
      a.x += v.x; a.y += v.y; a.z += v.z; a.w += v.w;
    }
    if (!LAST){
      uint2 pk = make_uint2(cvt_pk_bf16(a.x, a.y), cvt_pk_bf16(a.z, a.w));
      *(uint2*)(Sbt + ((size_t)o * NB + b) * ND + dq * 4) = pk;
    } else {
      tmp[0][dq][bl] = a;   // same-thread read-then-write of tmp[0]: safe
    }
  }
  if (LAST){
    __syncthreads();
    if (threadIdx.x < 32){
      int bb = bs * 32 + threadIdx.x;
      float4 sq[4];
      float s2 = 0.f;
      #pragma unroll
      for (int q = 0; q < 4; ++q){
        sq[q] = tmp[0][q][threadIdx.x];
        s2 += sq[q].x * sq[q].x + sq[q].y * sq[q].y + sq[q].z * sq[q].z + sq[q].w * sq[q].w;
      }
      float sc = (s2 / (1.f + s2)) / (sqrtf(s2) + 1e-8f);
      #pragma unroll
      for (int q = 0; q < 4; ++q)
        *(float4*)(out + ((size_t)bb * NO + o) * ND + 4 * q) =
          make_float4(sq[q].x * sc, sq[q].y * sc, sq[q].z * sc, sq[q].w * sc);
    }
  }
}

// dotacc: per block (ch of 8 i, bq of 64 b): dot via MFMA(WTb,Sbt) -> db -> L -> softmax
// -> c (LDS) -> c-weighted MFMA accumulation -> bf16 Pq partial
// 1D grid 576, XCD-swizzled. Register preload of usq (+L when !FIRST) + xq for ILP;
// all preloaded arrays are read-only in this kernel (no race surface).
template<bool FIRST>
__global__ __launch_bounds__(256) void k_dotacc(const u16* __restrict__ xbf,
                                                const u16* __restrict__ WTb,
                                                const u16* __restrict__ Wb,
                                                const u16* __restrict__ Sbt,
                                                const u16* __restrict__ usq,
                                                u16* __restrict__ L,
                                                uint2* __restrict__ Pq){
  int bid = blockIdx.x;
  int swz = (bid & 7) * 72 + (bid >> 3);    // bijective: 576 = 8*72
  int ch = swz >> 2, bq = swz & 3, i0 = ch * PIC;
  int w = threadIdx.x >> 6, l = threadIdx.x & 63, g = l >> 4, col = l & 15;
  int b = bq * 64 + w * 16 + col;

  __shared__ float c_lds[NO][PIC][66];   // padded: g-lanes hit distinct banks

  // Preload (one overlap window). usq: read-only everywhere. L: read-only when !FIRST
  // (in FIRST it is write-only, so not preloaded). xq: read-only.
  ushort4 xqv[4];
  float usv[4][NO];
  float lv[4][NO];
  #pragma unroll
  for (int ip = 0; ip < PIC / 2; ++ip){
    int i = i0 + 2 * ip + (g >> 1);
    xqv[ip] = *(const ushort4*)(xbf + ((size_t)i * NB + b) * NK + 4 * (g & 1));
    #pragma unroll
    for (int o = 0; o < NO; ++o){
      usv[ip][o] = bf2f(usq[((size_t)o * NI + i) * NB + b]);
      if (!FIRST) lv[ip][o] = bf2f(L[((size_t)o * NI + i) * NB + b]);
    }
  }

  // S fragments + |S|^2
  s8v sb[NO];
  float s2v[NO];
  #pragma unroll
  for (int o = 0; o < NO; ++o){
    sb[o] = zero8();
    if (g < 2)
      sb[o] = *(const s8v*)(Sbt + ((size_t)o * NB + b) * ND + 8 * g);
    float s2 = 0.f;
    #pragma unroll
    for (int j = 0; j < 8; ++j){
      float v = bf2f((u16)sb[o][j]);
      s2 = fmaf(v, v, s2);
    }
    s2 += __shfl_xor(s2, 16);
    s2 += __shfl_xor(s2, 32);
    s2v[o] = s2;
  }

  // dot + softmax -> c into LDS (fully unrolled)
  #pragma unroll
  for (int ip = 0; ip < PIC / 2; ++ip){
    int i0p = i0 + 2 * ip;
    int i = i0p + (g >> 1);
    ushort4 xq = xqv[ip];
    float dots[NO];
    #pragma unroll
    for (int o = 0; o < NO; ++o){
      s8v a = zero8();
      if (g < 2){
        int ia = i0p + (col >> 3), ka = col & 7;
        a = *(const s8v*)(WTb + (((size_t)(o * NI + ia)) * NK + ka) * ND + 8 * g);
      }
      f4v c = {0.f, 0.f, 0.f, 0.f};
      c = __builtin_amdgcn_mfma_f32_16x16x32_bf16(a, sb[o], c, 0, 0, 0);
      float p = c[0] * bf2f(xq.x) + c[1] * bf2f(xq.y)
              + c[2] * bf2f(xq.z) + c[3] * bf2f(xq.w);
      p += __shfl_xor(p, 16);
      dots[o] = p;
    }
    float lg[NO];
    #pragma unroll
    for (int o = 0; o < NO; ++o){
      float us = usv[ip][o];
      float t2 = fmaxf(s2v[o] - 2.f * dots[o] + us, 0.f);
      float ut = dots[o] - us;
      float db = ut * t2 / ((1.f + t2) * (sqrtf(t2) + 1e-8f));  // single divide
      float lo = FIRST ? db : (lv[ip][o] + db);
      if (FIRST && ((g & 1) == 0)) L[((size_t)o * NI + i) * NB + b] = f2bf(lo);
      lg[o] = lo;
    }
    float m = lg[0];
    #pragma unroll
    for (int o = 1; o < NO; ++o) m = fmaxf(m, lg[o]);
    float den = 0.f;
    #pragma unroll
    for (int o = 0; o < NO; ++o){ lg[o] = __expf(lg[o] - m); den += lg[o]; }
    float inv = 1.f / den;
    if ((g & 1) == 0){
      int ii = 2 * ip + (g >> 1);
      #pragma unroll
      for (int o = 0; o < NO; ++o)
        c_lds[o][ii][w * 16 + col] = lg[o] * inv;
    }
  }
  __syncthreads();

  // acc: Pq[(o*4+g)*PCH+ch][b] = 4xbf16( sum over this block's 8 i of c * u )
  // xv fragments are o-invariant: hoist out of the o-loop.
  s8v xv0 = *(const s8v*)(xbf + ((size_t)(i0 + g) * NB + b) * NK);
  s8v xv1 = *(const s8v*)(xbf + ((size_t)(i0 + 4 + g) * NB + b) * NK);
  for (int o = 0; o < NO; ++o){
    f4v acc = {0.f, 0.f, 0.f, 0.f};
    #pragma unroll
    for (int kt = 0; kt < PIC / 4; ++kt){
      int il = i0 + kt * 4 + g;
      s8v a = *(const s8v*)(Wb + ((size_t)(o * NI + il) * ND + col) * NK);
      float cw = c_lds[o][kt * 4 + g][w * 16 + col];
      s8v xv = kt ? xv1 : xv0;
      u32 q0 = cvt_pk_bf16(bf2f((u16)xv[0]) * cw, bf2f((u16)xv[1]) * cw);
      u32 q1 = cvt_pk_bf16(bf2f((u16)xv[2]) * cw, bf2f((u16)xv[3]) * cw);
      u32 q2 = cvt_pk_bf16(bf2f((u16)xv[4]) * cw, bf2f((u16)xv[5]) * cw);
      u32 q3 = cvt_pk_bf16(bf2f((u16)xv[6]) * cw, bf2f((u16)xv[7]) * cw);
      uint4 qq = make_uint4(q0, q1, q2, q3);
      s8v bb = __builtin_bit_cast(s8v, qq);
      acc = __builtin_amdgcn_mfma_f32_16x16x32_bf16(a, bb, acc, 0, 0, 0);
    }
    uint2 v = make_uint2(cvt_pk_bf16(acc[0], acc[1]), cvt_pk_bf16(acc[2], acc[3]));
    Pq[((size_t)(o * 4 + g) * PCH + ch) * NB + b] = v;
  }
}

extern "C" void kernel_launch(void* const* d_in, const int* in_sizes, int n_in,
                              void* d_out, int out_size, void* d_ws, size_t ws_size,
                              hipStream_t stream){
  const float* x = (const float*)d_in[0];
  // d_in[1] (y) unused by the reference computation.
  const float* W = (const float*)d_in[2];
  float* out = (float*)d_out;
  char* ws = (char*)d_ws;

  const size_t xbf_b = (size_t)NI * NB * NK * sizeof(u16);             // 4.7 MB
  const size_t Wb_b  = (size_t)NO * NI * ND * NK * sizeof(u16);        // 2.95 MB
  const size_t usq_b = (size_t)NO * NI * NB * sizeof(u16);             // 5.9 MB
  const size_t L_b   = (size_t)NO * NI * NB * sizeof(u16);             // 5.9 MB
  const size_t Pq_b  = (size_t)NO * 4 * PCH * NB * sizeof(uint2);      // 11.8 MB
  const size_t Sbt_b = (size_t)NO * NB * ND * sizeof(u16);             // 80 KB

  size_t off = 0;
  u16*    xbf = (u16*)(ws + off);    off += xbf_b;
  u16*    Wb  = (u16*)(ws + off);    off += Wb_b;
  u16*    WTb = (u16*)(ws + off);    off += Wb_b;
  u16*    usq = (u16*)(ws + off);    off += usq_b;
  u16*    L   = (u16*)(ws + off);    off += L_b;
  uint2*  Pq  = (uint2*)(ws + off);  off += Pq_b;
  u16*    Sbt = (u16*)(ws + off);    off += Sbt_b;
  (void)ws_size; (void)in_sizes; (void)n_in; (void)out_size;

  k_prep<<<dim3(1008), 256, 0, stream>>>(x, W, xbf, Wb, WTb);

  // iter 0: uniform c = 0.1 -> partials + usq
  k_pass0<<<dim3(PCH * NO), 256, 0, stream>>>(xbf, Wb, usq, Pq);
  k_red<false><<<dim3(NO, 8), 512, 0, stream>>>(Pq, Sbt, out);
  k_dotacc<true><<<dim3(PCH * 4), 256, 0, stream>>>(xbf, WTb, Wb, Sbt, usq, L, Pq);

  // iter 1
  k_red<false><<<dim3(NO, 8), 512, 0, stream>>>(Pq, Sbt, out);
  k_dotacc<false><<<dim3(PCH * 4), 256, 0, stream>>>(xbf, WTb, Wb, Sbt, usq, L, Pq);

  // iter 2: reduce final accumulation + fused squash -> out
  k_red<true><<<dim3(NO, 8), 512, 0, stream>>>(Pq, Sbt, out);
}

// Round 19
// 107.064 us; speedup vs baseline: 1.1770x; 1.1770x over previous
//
#include <hip/hip_runtime.h>

#define NB 256
#define NO 10
#define NI 1152
#define NK 8
#define ND 16
#define PCH 144   // i-chunks for pass0/dotacc (PIC=8)
#define PIC 8

typedef unsigned short u16;
typedef unsigned int u32;
typedef __attribute__((ext_vector_type(8))) short s8v;   // 8 bf16 (MFMA A/B frag)
typedef __attribute__((ext_vector_type(4))) float f4v;   // MFMA C/D frag

__device__ __forceinline__ float bf2f(u16 h){ return __uint_as_float(((u32)h) << 16); }
__device__ __forceinline__ u16 f2bf(float f){
  u32 u = __float_as_uint(f);
  return (u16)((u + 0x7FFFu + ((u >> 16) & 1u)) >> 16);  // RNE
}
__device__ __forceinline__ u32 cvt_pk_bf16(float lo, float hi){
  u32 r;
  asm("v_cvt_pk_bf16_f32 %0, %1, %2" : "=v"(r) : "v"(lo), "v"(hi));
  return r;
}
__device__ __forceinline__ s8v zero8(){
  s8v z;
  #pragma unroll
  for (int j = 0; j < 8; ++j) z[j] = 0;
  return z;
}

// prep: blocks [0,288): x [b][i][k] f32 -> xbf [i][b][k] bf16 via LDS 32x32 tile
//       blocks [288,1008): W [o][i][d][k] -> Wb (same layout) + WTb [o][i][k][d]
__global__ __launch_bounds__(256) void k_prep(const float* __restrict__ x,
                                              const float* __restrict__ W,
                                              u16* __restrict__ xbf,
                                              u16* __restrict__ Wb,
                                              u16* __restrict__ WTb){
  int blk = blockIdx.x;
  if (blk < 288){
    __shared__ __align__(16) u16 tile[32][33][8];
    int i0 = (blk >> 3) * 32, b0 = (blk & 7) * 32;
    int t = threadIdx.x;
    int bl = t >> 3, seg = t & 7;    // phase 1: thread = (b-local, 4-i segment)
    const float* src = x + ((size_t)(b0 + bl) * NI + (i0 + seg * 4)) * NK;
    #pragma unroll
    for (int q = 0; q < 4; ++q){
      float4 v0 = *(const float4*)(src + q * 8);
      float4 v1 = *(const float4*)(src + q * 8 + 4);
      *(uint4*)(&tile[seg * 4 + q][bl][0]) =
        make_uint4(cvt_pk_bf16(v0.x, v0.y), cvt_pk_bf16(v0.z, v0.w),
                   cvt_pk_bf16(v1.x, v1.y), cvt_pk_bf16(v1.z, v1.w));
    }
    __syncthreads();
    int il = t >> 3, sb2 = t & 7;    // phase 2: thread = (i-local, 4-b segment)
    u16* dst = xbf + ((size_t)(i0 + il) * NB + b0 + sb2 * 4) * NK;
    #pragma unroll
    for (int q = 0; q < 4; ++q)
      *(uint4*)(dst + q * 8) = *(const uint4*)(&tile[il][sb2 * 4 + q][0]);
  } else {
    int t = (blk - 288) * 256 + threadIdx.x;   // one (o,i,d) row of 8 k per thread
    if (t < NO * NI * ND){
      int oi = t >> 4, d = t & 15;
      const float* src = W + (size_t)t * NK;
      float4 v0 = *(const float4*)(src);
      float4 v1 = *(const float4*)(src + 4);
      u32 p0 = cvt_pk_bf16(v0.x, v0.y), p1 = cvt_pk_bf16(v0.z, v0.w);
      u32 p2 = cvt_pk_bf16(v1.x, v1.y), p3 = cvt_pk_bf16(v1.z, v1.w);
      *(uint4*)(Wb + (size_t)t * NK) = make_uint4(p0, p1, p2, p3);
      u16 e[8] = {(u16)(p0 & 0xffff), (u16)(p0 >> 16), (u16)(p1 & 0xffff), (u16)(p1 >> 16),
                  (u16)(p2 & 0xffff), (u16)(p2 >> 16), (u16)(p3 & 0xffff), (u16)(p3 >> 16)};
      #pragma unroll
      for (int k = 0; k < 8; ++k)
        WTb[((size_t)oi * NK + k) * ND + d] = e[k];
    }
  }
}

// pass0: u-tiles via MFMA; usq bf16 [o][i][b]; Pq[(o*4+g)*PCH+ch][b] = 4xbf16(0.1*sum_i u)
// 1D grid 1440, XCD-swizzled (bijective)
__global__ __launch_bounds__(256) void k_pass0(const u16* __restrict__ xbf,
                                               const u16* __restrict__ Wb,
                                               u16* __restrict__ usq,
                                               uint2* __restrict__ Pq){
  int bid = blockIdx.x;
  int swz = (bid & 7) * 180 + (bid >> 3);   // bijective: 1440 = 8*180
  int o = swz % NO, ch = swz / NO, i0 = ch * PIC;
  int w = threadIdx.x >> 6, l = threadIdx.x & 63, g = l >> 4, col = l & 15;
  float s0[4][4];
  #pragma unroll
  for (int bt = 0; bt < 4; ++bt){
    #pragma unroll
    for (int j = 0; j < 4; ++j) s0[bt][j] = 0.f;
  }
  #pragma unroll
  for (int ii = 0; ii < PIC; ++ii){
    int i = i0 + ii;
    s8v a = zero8();
    if (g == 0)  // A[d=col][k=j]
      a = *(const s8v*)(Wb + ((size_t)(o * NI + i) * ND + col) * NK);
    #pragma unroll
    for (int bt = 0; bt < 4; ++bt){
      int b = (w * 4 + bt) * 16 + col;
      s8v bf = zero8();
      if (g == 0)  // B[k=j][n=col] = x[i][b][j]
        bf = *(const s8v*)(xbf + ((size_t)i * NB + b) * NK);
      f4v c = {0.f, 0.f, 0.f, 0.f};
      c = __builtin_amdgcn_mfma_f32_16x16x32_bf16(a, bf, c, 0, 0, 0);
      float uq = c[0]*c[0] + c[1]*c[1] + c[2]*c[2] + c[3]*c[3];
      uq += __shfl_xor(uq, 16);
      uq += __shfl_xor(uq, 32);
      if (g == 0) usq[((size_t)o * NI + i) * NB + b] = f2bf(uq);
      #pragma unroll
      for (int j = 0; j < 4; ++j) s0[bt][j] += c[j];
    }
  }
  #pragma unroll
  for (int bt = 0; bt < 4; ++bt){
    int b = (w * 4 + bt) * 16 + col;
    uint2 v = make_uint2(cvt_pk_bf16(0.1f * s0[bt][0], 0.1f * s0[bt][1]),
                         cvt_pk_bf16(0.1f * s0[bt][2], 0.1f * s0[bt][3]));
    Pq[((size_t)(o * 4 + g) * PCH + ch) * NB + b] = v;
  }
}

// red: grid (NO, 8); 512 thr = bl(32) x dq(4) x chq(4); 36 ch each + LDS 4-way combine.
// !LAST -> Sbt bf16 [o][b][d]; LAST -> squash -> out (k_final fused)
template<bool LAST>
__global__ __launch_bounds__(512) void k_red(const uint2* __restrict__ Pq,
                                             u16* __restrict__ Sbt,
                                             float* __restrict__ out){
  int o = blockIdx.x, bs = blockIdx.y;
  int bl = threadIdx.x & 31, dq = (threadIdx.x >> 5) & 3, chq = threadIdx.x >> 7;
  int b = bs * 32 + bl;
  const uint2* p = Pq + ((size_t)(o * 4 + dq) * PCH + chq * (PCH / 4)) * NB + b;
  float4 a = make_float4(0.f, 0.f, 0.f, 0.f);
  #pragma unroll 12
  for (int ch = 0; ch < PCH / 4; ++ch){
    uint2 v = p[(size_t)ch * NB];
    a.x += bf2f((u16)(v.x & 0xffff));
    a.y += bf2f((u16)(v.x >> 16));
    a.z += bf2f((u16)(v.y & 0xffff));
    a.w += bf2f((u16)(v.y >> 16));
  }
  __shared__ float4 tmp[3][4][32];   // partials from chq=1..3: [chq-1][dq][bl]
  if (chq) tmp[chq - 1][dq][bl] = a;
  __syncthreads();
  if (chq == 0){
    #pragma unroll
    for (int q = 0; q < 3; ++q){
      float4 v = tmp[q][dq][bl];
      a.x += v.x; a.y += v.y; a.z += v.z; a.w += v.w;
    }
    if (!LAST){
      uint2 pk = make_uint2(cvt_pk_bf16(a.x, a.y), cvt_pk_bf16(a.z, a.w));
      *(uint2*)(Sbt + ((size_t)o * NB + b) * ND + dq * 4) = pk;
    } else {
      tmp[0][dq][bl] = a;   // same-thread read-then-write of tmp[0]: safe
    }
  }
  if (LAST){
    __syncthreads();
    if (threadIdx.x < 32){
      int bb = bs * 32 + threadIdx.x;
      float4 sq[4];
      float s2 = 0.f;
      #pragma unroll
      for (int q = 0; q < 4; ++q){
        sq[q] = tmp[0][q][threadIdx.x];
        s2 += sq[q].x * sq[q].x + sq[q].y * sq[q].y + sq[q].z * sq[q].z + sq[q].w * sq[q].w;
      }
      float sc = (s2 / (1.f + s2)) / (sqrtf(s2) + 1e-8f);
      #pragma unroll
      for (int q = 0; q < 4; ++q)
        *(float4*)(out + ((size_t)bb * NO + o) * ND + 4 * q) =
          make_float4(sq[q].x * sc, sq[q].y * sc, sq[q].z * sc, sq[q].w * sc);
    }
  }
}

// dotacc: per block (ch of 8 i, bq of 64 b): dot via MFMA(WTb,Sbt) -> db -> L -> softmax
// -> c (LDS) -> c-weighted MFMA accumulation -> bf16 Pq partial
// 1D grid 576, XCD-swizzled. WTb slice (20 KB) staged in LDS: the dot loop's 40
// scattered global loads per thread become LDS reads (Guideline 3).
template<bool FIRST>
__global__ __launch_bounds__(256) void k_dotacc(const u16* __restrict__ xbf,
                                                const u16* __restrict__ WTb,
                                                const u16* __restrict__ Wb,
                                                const u16* __restrict__ Sbt,
                                                const u16* __restrict__ usq,
                                                u16* __restrict__ L,
                                                uint2* __restrict__ Pq){
  int bid = blockIdx.x;
  int swz = (bid & 7) * 72 + (bid >> 3);    // bijective: 576 = 8*72
  int ch = swz >> 2, bq = swz & 3, i0 = ch * PIC;
  int w = threadIdx.x >> 6, l = threadIdx.x & 63, g = l >> 4, col = l & 15;
  int b = bq * 64 + w * 16 + col;

  __shared__ float c_lds[NO][PIC][66];              // padded: g-lanes hit distinct banks
  __shared__ __align__(16) u16 WTs[NO * PIC * NK * ND];  // [o][i-i0][k][d], 20480 B

  // Cooperative stage: per o, the 8-i slice of WTb is 1024 contiguous u16 (2 KB).
  // 1280 x 16B chunks over 256 threads = 5 each, fully coalesced.
  #pragma unroll
  for (int rep = 0; rep < 5; ++rep){
    int idx = rep * 256 + threadIdx.x;     // 0..1279
    int oo = idx >> 7, within = idx & 127; // 128 x 16B per o
    *(uint4*)(WTs + ((size_t)oo * 128 + within) * 8) =
      *(const uint4*)(WTb + ((size_t)(oo * NI) + i0) * (NK * ND) + (size_t)within * 8);
  }
  __syncthreads();

  // S fragments + |S|^2
  s8v sb[NO];
  float s2v[NO];
  #pragma unroll
  for (int o = 0; o < NO; ++o){
    sb[o] = zero8();
    if (g < 2)
      sb[o] = *(const s8v*)(Sbt + ((size_t)o * NB + b) * ND + 8 * g);
    float s2 = 0.f;
    #pragma unroll
    for (int j = 0; j < 8; ++j){
      float v = bf2f((u16)sb[o][j]);
      s2 = fmaf(v, v, s2);
    }
    s2 += __shfl_xor(s2, 16);
    s2 += __shfl_xor(s2, 32);
    s2v[o] = s2;
  }

  // dot + softmax -> c into LDS (fully unrolled); A-frags from LDS (WTs)
  #pragma unroll
  for (int ip = 0; ip < PIC / 2; ++ip){
    int i0p = i0 + 2 * ip;
    int i = i0p + (g >> 1);
    int kb = 4 * (g & 1);
    ushort4 xq = *(const ushort4*)(xbf + ((size_t)i * NB + b) * NK + kb);
    int ia_loc = 2 * ip + (col >> 3), ka = col & 7;
    float dots[NO];
    #pragma unroll
    for (int o = 0; o < NO; ++o){
      s8v a = zero8();
      if (g < 2)   // A[r=col][kd=8g+j] = WTs[o][ia_loc][ka][8g..]
        a = *(const s8v*)(WTs + (((size_t)o * PIC + ia_loc) * NK + ka) * ND + 8 * g);
      f4v c = {0.f, 0.f, 0.f, 0.f};
      c = __builtin_amdgcn_mfma_f32_16x16x32_bf16(a, sb[o], c, 0, 0, 0);
      float p = c[0] * bf2f(xq.x) + c[1] * bf2f(xq.y)
              + c[2] * bf2f(xq.z) + c[3] * bf2f(xq.w);
      p += __shfl_xor(p, 16);
      dots[o] = p;
    }
    float lg[NO];
    #pragma unroll
    for (int o = 0; o < NO; ++o){
      float us = bf2f(usq[((size_t)o * NI + i) * NB + b]);
      float t2 = fmaxf(s2v[o] - 2.f * dots[o] + us, 0.f);
      float ut = dots[o] - us;
      float db = ut * t2 / ((1.f + t2) * (sqrtf(t2) + 1e-8f));  // single divide
      float lo = FIRST ? db : (bf2f(L[((size_t)o * NI + i) * NB + b]) + db);
      if (FIRST && ((g & 1) == 0)) L[((size_t)o * NI + i) * NB + b] = f2bf(lo);
      lg[o] = lo;
    }
    float m = lg[0];
    #pragma unroll
    for (int o = 1; o < NO; ++o) m = fmaxf(m, lg[o]);
    float den = 0.f;
    #pragma unroll
    for (int o = 0; o < NO; ++o){ lg[o] = __expf(lg[o] - m); den += lg[o]; }
    float inv = 1.f / den;
    if ((g & 1) == 0){
      int ii = 2 * ip + (g >> 1);
      #pragma unroll
      for (int o = 0; o < NO; ++o)
        c_lds[o][ii][w * 16 + col] = lg[o] * inv;
    }
  }
  __syncthreads();

  // acc: Pq[(o*4+g)*PCH+ch][b] = 4xbf16( sum over this block's 8 i of c * u )
  // xv fragments are o-invariant: hoist out of the o-loop.
  s8v xv0 = *(const s8v*)(xbf + ((size_t)(i0 + g) * NB + b) * NK);
  s8v xv1 = *(const s8v*)(xbf + ((size_t)(i0 + 4 + g) * NB + b) * NK);
  for (int o = 0; o < NO; ++o){
    f4v acc = {0.f, 0.f, 0.f, 0.f};
    #pragma unroll
    for (int kt = 0; kt < PIC / 4; ++kt){
      int il = i0 + kt * 4 + g;
      s8v a = *(const s8v*)(Wb + ((size_t)(o * NI + il) * ND + col) * NK);
      float cw = c_lds[o][kt * 4 + g][w * 16 + col];
      s8v xv = kt ? xv1 : xv0;
      u32 q0 = cvt_pk_bf16(bf2f((u16)xv[0]) * cw, bf2f((u16)xv[1]) * cw);
      u32 q1 = cvt_pk_bf16(bf2f((u16)xv[2]) * cw, bf2f((u16)xv[3]) * cw);
      u32 q2 = cvt_pk_bf16(bf2f((u16)xv[4]) * cw, bf2f((u16)xv[5]) * cw);
      u32 q3 = cvt_pk_bf16(bf2f((u16)xv[6]) * cw, bf2f((u16)xv[7]) * cw);
      uint4 qq = make_uint4(q0, q1, q2, q3);
      s8v bb = __builtin_bit_cast(s8v, qq);
      acc = __builtin_amdgcn_mfma_f32_16x16x32_bf16(a, bb, acc, 0, 0, 0);
    }
    uint2 v = make_uint2(cvt_pk_bf16(acc[0], acc[1]), cvt_pk_bf16(acc[2], acc[3]));
    Pq[((size_t)(o * 4 + g) * PCH + ch) * NB + b] = v;
  }
}

extern "C" void kernel_launch(void* const* d_in, const int* in_sizes, int n_in,
                              void* d_out, int out_size, void* d_ws, size_t ws_size,
                              hipStream_t stream){
  const float* x = (const float*)d_in[0];
  // d_in[1] (y) unused by the reference computation.
  const float* W = (const float*)d_in[2];
  float* out = (float*)d_out;
  char* ws = (char*)d_ws;

  const size_t xbf_b = (size_t)NI * NB * NK * sizeof(u16);             // 4.7 MB
  const size_t Wb_b  = (size_t)NO * NI * ND * NK * sizeof(u16);        // 2.95 MB
  const size_t usq_b = (size_t)NO * NI * NB * sizeof(u16);             // 5.9 MB
  const size_t L_b   = (size_t)NO * NI * NB * sizeof(u16);             // 5.9 MB
  const size_t Pq_b  = (size_t)NO * 4 * PCH * NB * sizeof(uint2);      // 11.8 MB
  const size_t Sbt_b = (size_t)NO * NB * ND * sizeof(u16);             // 80 KB

  size_t off = 0;
  u16*    xbf = (u16*)(ws + off);    off += xbf_b;
  u16*    Wb  = (u16*)(ws + off);    off += Wb_b;
  u16*    WTb = (u16*)(ws + off);    off += Wb_b;
  u16*    usq = (u16*)(ws + off);    off += usq_b;
  u16*    L   = (u16*)(ws + off);    off += L_b;
  uint2*  Pq  = (uint2*)(ws + off);  off += Pq_b;
  u16*    Sbt = (u16*)(ws + off);    off += Sbt_b;
  (void)ws_size; (void)in_sizes; (void)n_in; (void)out_size;

  k_prep<<<dim3(1008), 256, 0, stream>>>(x, W, xbf, Wb, WTb);

  // iter 0: uniform c = 0.1 -> partials + usq
  k_pass0<<<dim3(PCH * NO), 256, 0, stream>>>(xbf, Wb, usq, Pq);
  k_red<false><<<dim3(NO, 8), 512, 0, stream>>>(Pq, Sbt, out);
  k_dotacc<true><<<dim3(PCH * 4), 256, 0, stream>>>(xbf, WTb, Wb, Sbt, usq, L, Pq);

  // iter 1
  k_red<false><<<dim3(NO, 8), 512, 0, stream>>>(Pq, Sbt, out);
  k_dotacc<false><<<dim3(PCH * 4), 256, 0, stream>>>(xbf, WTb, Wb, Sbt, usq, L, Pq);

  // iter 2: reduce final accumulation + fused squash -> out
  k_red<true><<<dim3(NO, 8), 512, 0, stream>>>(Pq, Sbt, out);
}

// Round 20
// 101.123 us; speedup vs baseline: 1.2462x; 1.0588x over previous
//
#include <hip/hip_runtime.h>

#define NB 256
#define NO 10
#define NI 1152
#define NK 8
#define ND 16
#define PCH 144   // i-chunks for pass0/dotacc (PIC=8)
#define PIC 8

typedef unsigned short u16;
typedef unsigned int u32;
typedef __attribute__((ext_vector_type(8))) short s8v;   // 8 bf16 (MFMA A/B frag)
typedef __attribute__((ext_vector_type(4))) float f4v;   // MFMA C/D frag

__device__ __forceinline__ float bf2f(u16 h){ return __uint_as_float(((u32)h) << 16); }
__device__ __forceinline__ u16 f2bf(float f){
  u32 u = __float_as_uint(f);
  return (u16)((u + 0x7FFFu + ((u >> 16) & 1u)) >> 16);  // RNE
}
__device__ __forceinline__ u32 cvt_pk_bf16(float lo, float hi){
  u32 r;
  asm("v_cvt_pk_bf16_f32 %0, %1, %2" : "=v"(r) : "v"(lo), "v"(hi));
  return r;
}
__device__ __forceinline__ s8v zero8(){
  s8v z;
  #pragma unroll
  for (int j = 0; j < 8; ++j) z[j] = 0;
  return z;
}

// prep: blocks [0,288): x [b][i][k] f32 -> xbf [i][b][k] bf16 via LDS 32x32 tile
//       blocks [288,1008): W [o][i][d][k] -> Wb (same layout) + WTb [o][i][k][d]
__global__ __launch_bounds__(256) void k_prep(const float* __restrict__ x,
                                              const float* __restrict__ W,
                                              u16* __restrict__ xbf,
                                              u16* __restrict__ Wb,
                                              u16* __restrict__ WTb){
  int blk = blockIdx.x;
  if (blk < 288){
    __shared__ __align__(16) u16 tile[32][33][8];
    int i0 = (blk >> 3) * 32, b0 = (blk & 7) * 32;
    int t = threadIdx.x;
    int bl = t >> 3, seg = t & 7;    // phase 1: thread = (b-local, 4-i segment)
    const float* src = x + ((size_t)(b0 + bl) * NI + (i0 + seg * 4)) * NK;
    #pragma unroll
    for (int q = 0; q < 4; ++q){
      float4 v0 = *(const float4*)(src + q * 8);
      float4 v1 = *(const float4*)(src + q * 8 + 4);
      *(uint4*)(&tile[seg * 4 + q][bl][0]) =
        make_uint4(cvt_pk_bf16(v0.x, v0.y), cvt_pk_bf16(v0.z, v0.w),
                   cvt_pk_bf16(v1.x, v1.y), cvt_pk_bf16(v1.z, v1.w));
    }
    __syncthreads();
    int il = t >> 3, sb2 = t & 7;    // phase 2: thread = (i-local, 4-b segment)
    u16* dst = xbf + ((size_t)(i0 + il) * NB + b0 + sb2 * 4) * NK;
    #pragma unroll
    for (int q = 0; q < 4; ++q)
      *(uint4*)(dst + q * 8) = *(const uint4*)(&tile[il][sb2 * 4 + q][0]);
  } else {
    int t = (blk - 288) * 256 + threadIdx.x;   // one (o,i,d) row of 8 k per thread
    if (t < NO * NI * ND){
      int oi = t >> 4, d = t & 15;
      const float* src = W + (size_t)t * NK;
      float4 v0 = *(const float4*)(src);
      float4 v1 = *(const float4*)(src + 4);
      u32 p0 = cvt_pk_bf16(v0.x, v0.y), p1 = cvt_pk_bf16(v0.z, v0.w);
      u32 p2 = cvt_pk_bf16(v1.x, v1.y), p3 = cvt_pk_bf16(v1.z, v1.w);
      *(uint4*)(Wb + (size_t)t * NK) = make_uint4(p0, p1, p2, p3);
      u16 e[8] = {(u16)(p0 & 0xffff), (u16)(p0 >> 16), (u16)(p1 & 0xffff), (u16)(p1 >> 16),
                  (u16)(p2 & 0xffff), (u16)(p2 >> 16), (u16)(p3 & 0xffff), (u16)(p3 >> 16)};
      #pragma unroll
      for (int k = 0; k < 8; ++k)
        WTb[((size_t)oi * NK + k) * ND + d] = e[k];
    }
  }
}

// pass0: u-tiles via MFMA; usq bf16 [o][i][b]; Pq[(o*4+g)*PCH+ch][b] = 4xbf16(0.1*sum_i u)
// 1D grid 1440, XCD-swizzled (bijective)
__global__ __launch_bounds__(256) void k_pass0(const u16* __restrict__ xbf,
                                               const u16* __restrict__ Wb,
                                               u16* __restrict__ usq,
                                               uint2* __restrict__ Pq){
  int bid = blockIdx.x;
  int swz = (bid & 7) * 180 + (bid >> 3);   // bijective: 1440 = 8*180
  int o = swz % NO, ch = swz / NO, i0 = ch * PIC;
  int w = threadIdx.x >> 6, l = threadIdx.x & 63, g = l >> 4, col = l & 15;
  float s0[4][4];
  #pragma unroll
  for (int bt = 0; bt < 4; ++bt){
    #pragma unroll
    for (int j = 0; j < 4; ++j) s0[bt][j] = 0.f;
  }
  #pragma unroll
  for (int ii = 0; ii < PIC; ++ii){
    int i = i0 + ii;
    s8v a = zero8();
    if (g == 0)  // A[d=col][k=j]
      a = *(const s8v*)(Wb + ((size_t)(o * NI + i) * ND + col) * NK);
    #pragma unroll
    for (int bt = 0; bt < 4; ++bt){
      int b = (w * 4 + bt) * 16 + col;
      s8v bf = zero8();
      if (g == 0)  // B[k=j][n=col] = x[i][b][j]
        bf = *(const s8v*)(xbf + ((size_t)i * NB + b) * NK);
      f4v c = {0.f, 0.f, 0.f, 0.f};
      c = __builtin_amdgcn_mfma_f32_16x16x32_bf16(a, bf, c, 0, 0, 0);
      float uq = c[0]*c[0] + c[1]*c[1] + c[2]*c[2] + c[3]*c[3];
      uq += __shfl_xor(uq, 16);
      uq += __shfl_xor(uq, 32);
      if (g == 0) usq[((size_t)o * NI + i) * NB + b] = f2bf(uq);
      #pragma unroll
      for (int j = 0; j < 4; ++j) s0[bt][j] += c[j];
    }
  }
  #pragma unroll
  for (int bt = 0; bt < 4; ++bt){
    int b = (w * 4 + bt) * 16 + col;
    uint2 v = make_uint2(cvt_pk_bf16(0.1f * s0[bt][0], 0.1f * s0[bt][1]),
                         cvt_pk_bf16(0.1f * s0[bt][2], 0.1f * s0[bt][3]));
    Pq[((size_t)(o * 4 + g) * PCH + ch) * NB + b] = v;
  }
}

// red: grid (NO, 8); 512 thr = bl(32) x dq(4) x chq(4); 36 ch each + LDS 4-way combine.
// !LAST -> Sbt bf16 [o][b][d]; LAST -> squash -> out (k_final fused)
template<bool LAST>
__global__ __launch_bounds__(512) void k_red(const uint2* __restrict__ Pq,
                                             u16* __restrict__ Sbt,
                                             float* __restrict__ out){
  int o = blockIdx.x, bs = blockIdx.y;
  int bl = threadIdx.x & 31, dq = (threadIdx.x >> 5) & 3, chq = threadIdx.x >> 7;
  int b = bs * 32 + bl;
  const uint2* p = Pq + ((size_t)(o * 4 + dq) * PCH + chq * (PCH / 4)) * NB + b;
  float4 a = make_float4(0.f, 0.f, 0.f, 0.f);
  #pragma unroll 12
  for (int ch = 0; ch < PCH / 4; ++ch){
    uint2 v = p[(size_t)ch * NB];
    a.x += bf2f((u16)(v.x & 0xffff));
    a.y += bf2f((u16)(v.x >> 16));
    a.z += bf2f((u16)(v.y & 0xffff));
    a.w += bf2f((u16)(v.y >> 16));
  }
  __shared__ float4 tmp[3][4][32];   // partials from chq=1..3: [chq-1][dq][bl]
  if (chq) tmp[chq - 1][dq][bl] = a;
  __syncthreads();
  if (chq == 0){
    #pragma unroll
    for (int q = 0; q < 3; ++q){
      float4 v = tmp[q][dq][bl];
      a.x += v.x; a.y += v.y; a.z += v.z; a.w += v.w;
    }
    if (!LAST){
      uint2 pk = make_uint2(cvt_pk_bf16(a.x, a.y), cvt_pk_bf16(a.z, a.w));
      *(uint2*)(Sbt + ((size_t)o * NB + b) * ND + dq * 4) = pk;
    } else {
      tmp[0][dq][bl] = a;   // same-thread read-then-write of tmp[0]: safe
    }
  }
  if (LAST){
    __syncthreads();
    if (threadIdx.x < 32){
      int bb = bs * 32 + threadIdx.x;
      float4 sq[4];
      float s2 = 0.f;
      #pragma unroll
      for (int q = 0; q < 4; ++q){
        sq[q] = tmp[0][q][threadIdx.x];
        s2 += sq[q].x * sq[q].x + sq[q].y * sq[q].y + sq[q].z * sq[q].z + sq[q].w * sq[q].w;
      }
      float sc = (s2 / (1.f + s2)) / (sqrtf(s2) + 1e-8f);
      #pragma unroll
      for (int q = 0; q < 4; ++q)
        *(float4*)(out + ((size_t)bb * NO + o) * ND + 4 * q) =
          make_float4(sq[q].x * sc, sq[q].y * sc, sq[q].z * sc, sq[q].w * sc);
    }
  }
}

// dotacc: per block (ch of 8 i, bq of 64 b): dot via MFMA(WTb,Sbt) -> db -> L -> softmax
// -> c (LDS) -> c-weighted MFMA accumulation -> bf16 Pq partial
// 1D grid 576, XCD-swizzled. WTb slice (20 KB) AND usq slice (10 KB) staged in LDS:
// the dot loop's scattered global loads become LDS reads (Guideline 3).
template<bool FIRST>
__global__ __launch_bounds__(256) void k_dotacc(const u16* __restrict__ xbf,
                                                const u16* __restrict__ WTb,
                                                const u16* __restrict__ Wb,
                                                const u16* __restrict__ Sbt,
                                                const u16* __restrict__ usq,
                                                u16* __restrict__ L,
                                                uint2* __restrict__ Pq){
  int bid = blockIdx.x;
  int swz = (bid & 7) * 72 + (bid >> 3);    // bijective: 576 = 8*72
  int ch = swz >> 2, bq = swz & 3, i0 = ch * PIC;
  int w = threadIdx.x >> 6, l = threadIdx.x & 63, g = l >> 4, col = l & 15;
  int b = bq * 64 + w * 16 + col;

  __shared__ float c_lds[NO][PIC][66];                   // padded: g-lanes hit distinct banks
  __shared__ __align__(16) u16 WTs[NO * PIC * NK * ND];  // [o][i-i0][k][d], 20480 B
  __shared__ __align__(16) u16 usq_s[NO][PIC][72];       // [o][i-i0][b-local], 11520 B (row pad 4 banks)

  // Cooperative stage of WTb slice: 1280 x 16B chunks over 256 threads = 5 each, coalesced.
  #pragma unroll
  for (int rep = 0; rep < 5; ++rep){
    int idx = rep * 256 + threadIdx.x;     // 0..1279
    int oo = idx >> 7, within = idx & 127; // 128 x 16B per o
    *(uint4*)(WTs + ((size_t)oo * 128 + within) * 8) =
      *(const uint4*)(WTb + ((size_t)(oo * NI) + i0) * (NK * ND) + (size_t)within * 8);
  }
  // Cooperative stage of usq slice: 80 rows (o,ii) x 64 b = 640 x 16B chunks.
  #pragma unroll
  for (int rep = 0; rep < 3; ++rep){
    int idx = rep * 256 + threadIdx.x;
    if (idx < 640){
      int row = idx >> 3, seg = idx & 7;   // 8 x 16B per row
      int oo = row >> 3, ii = row & 7;
      *(uint4*)(&usq_s[oo][ii][seg * 8]) =
        *(const uint4*)(usq + ((size_t)(oo * NI) + i0 + ii) * NB + bq * 64 + seg * 8);
    }
  }
  __syncthreads();

  // S fragments + |S|^2
  s8v sb[NO];
  float s2v[NO];
  #pragma unroll
  for (int o = 0; o < NO; ++o){
    sb[o] = zero8();
    if (g < 2)
      sb[o] = *(const s8v*)(Sbt + ((size_t)o * NB + b) * ND + 8 * g);
    float s2 = 0.f;
    #pragma unroll
    for (int j = 0; j < 8; ++j){
      float v = bf2f((u16)sb[o][j]);
      s2 = fmaf(v, v, s2);
    }
    s2 += __shfl_xor(s2, 16);
    s2 += __shfl_xor(s2, 32);
    s2v[o] = s2;
  }

  // dot + softmax -> c into LDS (fully unrolled); A-frags and usq from LDS
  #pragma unroll
  for (int ip = 0; ip < PIC / 2; ++ip){
    int i0p = i0 + 2 * ip;
    int i = i0p + (g >> 1);
    int iloc = 2 * ip + (g >> 1);
    int kb = 4 * (g & 1);
    ushort4 xq = *(const ushort4*)(xbf + ((size_t)i * NB + b) * NK + kb);
    int ia_loc = 2 * ip + (col >> 3), ka = col & 7;
    float dots[NO];
    #pragma unroll
    for (int o = 0; o < NO; ++o){
      s8v a = zero8();
      if (g < 2)   // A[r=col][kd=8g+j] = WTs[o][ia_loc][ka][8g..]
        a = *(const s8v*)(WTs + (((size_t)o * PIC + ia_loc) * NK + ka) * ND + 8 * g);
      f4v c = {0.f, 0.f, 0.f, 0.f};
      c = __builtin_amdgcn_mfma_f32_16x16x32_bf16(a, sb[o], c, 0, 0, 0);
      float p = c[0] * bf2f(xq.x) + c[1] * bf2f(xq.y)
              + c[2] * bf2f(xq.z) + c[3] * bf2f(xq.w);
      p += __shfl_xor(p, 16);
      dots[o] = p;
    }
    float lg[NO];
    #pragma unroll
    for (int o = 0; o < NO; ++o){
      float us = bf2f(usq_s[o][iloc][w * 16 + col]);
      float t2 = fmaxf(s2v[o] - 2.f * dots[o] + us, 0.f);
      float ut = dots[o] - us;
      float db = ut * t2 / ((1.f + t2) * (sqrtf(t2) + 1e-8f));  // single divide
      float lo = FIRST ? db : (bf2f(L[((size_t)o * NI + i) * NB + b]) + db);
      if (FIRST && ((g & 1) == 0)) L[((size_t)o * NI + i) * NB + b] = f2bf(lo);
      lg[o] = lo;
    }
    float m = lg[0];
    #pragma unroll
    for (int o = 1; o < NO; ++o) m = fmaxf(m, lg[o]);
    float den = 0.f;
    #pragma unroll
    for (int o = 0; o < NO; ++o){ lg[o] = __expf(lg[o] - m); den += lg[o]; }
    float inv = 1.f / den;
    if ((g & 1) == 0){
      int ii = 2 * ip + (g >> 1);
      #pragma unroll
      for (int o = 0; o < NO; ++o)
        c_lds[o][ii][w * 16 + col] = lg[o] * inv;
    }
  }
  __syncthreads();

  // acc: Pq[(o*4+g)*PCH+ch][b] = 4xbf16( sum over this block's 8 i of c * u )
  // xv fragments are o-invariant: hoist out of the o-loop.
  s8v xv0 = *(const s8v*)(xbf + ((size_t)(i0 + g) * NB + b) * NK);
  s8v xv1 = *(const s8v*)(xbf + ((size_t)(i0 + 4 + g) * NB + b) * NK);
  for (int o = 0; o < NO; ++o){
    f4v acc = {0.f, 0.f, 0.f, 0.f};
    #pragma unroll
    for (int kt = 0; kt < PIC / 4; ++kt){
      int il = i0 + kt * 4 + g;
      s8v a = *(const s8v*)(Wb + ((size_t)(o * NI + il) * ND + col) * NK);
      float cw = c_lds[o][kt * 4 + g][w * 16 + col];
      s8v xv = kt ? xv1 : xv0;
      u32 q0 = cvt_pk_bf16(bf2f((u16)xv[0]) * cw, bf2f((u16)xv[1]) * cw);
      u32 q1 = cvt_pk_bf16(bf2f((u16)xv[2]) * cw, bf2f((u16)xv[3]) * cw);
      u32 q2 = cvt_pk_bf16(bf2f((u16)xv[4]) * cw, bf2f((u16)xv[5]) * cw);
      u32 q3 = cvt_pk_bf16(bf2f((u16)xv[6]) * cw, bf2f((u16)xv[7]) * cw);
      uint4 qq = make_uint4(q0, q1, q2, q3);
      s8v bb = __builtin_bit_cast(s8v, qq);
      acc = __builtin_amdgcn_mfma_f32_16x16x32_bf16(a, bb, acc, 0, 0, 0);
    }
    uint2 v = make_uint2(cvt_pk_bf16(acc[0], acc[1]), cvt_pk_bf16(acc[2], acc[3]));
    Pq[((size_t)(o * 4 + g) * PCH + ch) * NB + b] = v;
  }
}

extern "C" void kernel_launch(void* const* d_in, const int* in_sizes, int n_in,
                              void* d_out, int out_size, void* d_ws, size_t ws_size,
                              hipStream_t stream){
  const float* x = (const float*)d_in[0];
  // d_in[1] (y) unused by the reference computation.
  const float* W = (const float*)d_in[2];
  float* out = (float*)d_out;
  char* ws = (char*)d_ws;

  const size_t xbf_b = (size_t)NI * NB * NK * sizeof(u16);             // 4.7 MB
  const size_t Wb_b  = (size_t)NO * NI * ND * NK * sizeof(u16);        // 2.95 MB
  const size_t usq_b = (size_t)NO * NI * NB * sizeof(u16);             // 5.9 MB
  const size_t L_b   = (size_t)NO * NI * NB * sizeof(u16);             // 5.9 MB
  const size_t Pq_b  = (size_t)NO * 4 * PCH * NB * sizeof(uint2);      // 11.8 MB
  const size_t Sbt_b = (size_t)NO * NB * ND * sizeof(u16);             // 80 KB

  size_t off = 0;
  u16*    xbf = (u16*)(ws + off);    off += xbf_b;
  u16*    Wb  = (u16*)(ws + off);    off += Wb_b;
  u16*    WTb = (u16*)(ws + off);    off += Wb_b;
  u16*    usq = (u16*)(ws + off);    off += usq_b;
  u16*    L   = (u16*)(ws + off);    off += L_b;
  uint2*  Pq  = (uint2*)(ws + off);  off += Pq_b;
  u16*    Sbt = (u16*)(ws + off);    off += Sbt_b;
  (void)ws_size; (void)in_sizes; (void)n_in; (void)out_size;

  k_prep<<<dim3(1008), 256, 0, stream>>>(x, W, xbf, Wb, WTb);

  // iter 0: uniform c = 0.1 -> partials + usq
  k_pass0<<<dim3(PCH * NO), 256, 0, stream>>>(xbf, Wb, usq, Pq);
  k_red<false><<<dim3(NO, 8), 512, 0, stream>>>(Pq, Sbt, out);
  k_dotacc<true><<<dim3(PCH * 4), 256, 0, stream>>>(xbf, WTb, Wb, Sbt, usq, L, Pq);

  // iter 1
  k_red<false><<<dim3(NO, 8), 512, 0, stream>>>(Pq, Sbt, out);
  k_dotacc<false><<<dim3(PCH * 4), 256, 0, stream>>>(xbf, WTb, Wb, Sbt, usq, L, Pq);

  // iter 2: reduce final accumulation + fused squash -> out
  k_red<true><<<dim3(NO, 8), 512, 0, stream>>>(Pq, Sbt, out);
}